// Round 4
// baseline (172.944 us; speedup 1.0000x reference)
//
#include <hip/hip_runtime.h>

#define NROWS 8192
#define DH 128
#define NTILES 256            // NROWS / 32
#define NWAVES 4
#define BQ_WG 128             // 4 waves * 32 q rows
#define TILE_SHORTS 12288     // 24KB per K tile: kh 4096 + kl 4096 + vt 4096 shorts

typedef float f32x16 __attribute__((ext_vector_type(16)));
typedef float f32x4  __attribute__((ext_vector_type(4)));
typedef short s16x8  __attribute__((ext_vector_type(8)));

#define MFMA(a, b, c) __builtin_amdgcn_mfma_f32_32x32x16_bf16(a, b, c, 0, 0, 0)
#define EXP2F(x) __builtin_amdgcn_exp2f(x)

// fp32 -> bf16 bits (RNE)
__device__ __forceinline__ short f2bf(float x) {
    unsigned u = __float_as_uint(x);
    unsigned r = (u + 0x7fffu + ((u >> 16) & 1u)) >> 16;
    return (short)r;
}
__device__ __forceinline__ float bf2f(short s) {
    return __uint_as_float(((unsigned)(unsigned short)s) << 16);
}

// log2-domain combined scale: sqrt(8192) * log2(e)
#define CSC 130.577849f
// defer-max threshold (log2 domain): P bounded by 2^8
#define RESC_THR 8.0f

__device__ __forceinline__ void gload16(const short* g, short* l) {
    __builtin_amdgcn_global_load_lds(
        (const __attribute__((address_space(1))) unsigned*)g,
        (__attribute__((address_space(3))) unsigned*)l, 16, 0, 0);
}

// ---------------------------------------------------------------------------
// prep: convert p2 (fp32) into per-tile swizzled LDS images in ws:
//   per 32-row tile t: [kh 8KB][kl 8KB][vt 8KB] contiguous (24KB)
//   kh/kl: idx = (r*128 + d) ^ ((r&7)<<3)           (short units)
//   vt   : idx = (d*32 + k) ^ (((d>>1)&3)<<3)       (short units, word writes)
// ---------------------------------------------------------------------------
__global__ __launch_bounds__(256) void prep(const float* __restrict__ KV,
                                            short* __restrict__ kws)
{
    const int t = blockIdx.x;
    const int tid = threadIdx.x;
    short* kh = kws + (size_t)t * TILE_SHORTS;
    short* kl = kh + 4096;
    short* vt = kh + 8192;

    // ---- Kh / Kl (each thread: one row-slice of 16 floats)
    {
        const int r  = tid >> 3;            // 0..31
        const int d0 = (tid & 7) << 4;      // 0,16,..,112
        const float* src = KV + ((size_t)(t * 32 + r)) * DH + d0;
        f32x4 a0 = *(const f32x4*)(src);
        f32x4 a1 = *(const f32x4*)(src + 4);
        f32x4 a2 = *(const f32x4*)(src + 8);
        f32x4 a3 = *(const f32x4*)(src + 12);
        s16x8 h0, h1, l0, l1;
        #pragma unroll
        for (int j = 0; j < 4; ++j) {
            { float x = a0[j]; short h = f2bf(x); h0[j]     = h; l0[j]     = f2bf(x - bf2f(h)); }
            { float x = a1[j]; short h = f2bf(x); h0[j + 4] = h; l0[j + 4] = f2bf(x - bf2f(h)); }
            { float x = a2[j]; short h = f2bf(x); h1[j]     = h; l1[j]     = f2bf(x - bf2f(h)); }
            { float x = a3[j]; short h = f2bf(x); h1[j + 4] = h; l1[j + 4] = f2bf(x - bf2f(h)); }
        }
        const int base = r * 128 + d0;
        const int swz  = (r & 7) << 3;
        *(s16x8*)&kh[(base    ) ^ swz] = h0;
        *(s16x8*)&kh[(base + 8) ^ swz] = h1;
        *(s16x8*)&kl[(base    ) ^ swz] = l0;
        *(s16x8*)&kl[(base + 8) ^ swz] = l1;
    }

    // ---- Vt (transposed bf16-hi of the same tile)
    {
        const int pr = tid & 15;        // row pair
        const int c8 = tid >> 4;        // d block
        const int r0 = pr * 2;
        const float* sa = KV + ((size_t)(t * 32 + r0)) * DH + c8 * 8;
        const float* sb = sa + DH;
        f32x4 a0 = *(const f32x4*)(sa);
        f32x4 a1 = *(const f32x4*)(sa + 4);
        f32x4 b0 = *(const f32x4*)(sb);
        f32x4 b1 = *(const f32x4*)(sb + 4);
        #pragma unroll
        for (int i = 0; i < 8; ++i) {
            int d = c8 * 8 + i;
            float xa = (i < 4) ? a0[i] : a1[i - 4];
            float xb = (i < 4) ? b0[i] : b1[i - 4];
            unsigned w = ((unsigned)(unsigned short)f2bf(xb) << 16) |
                         (unsigned short)f2bf(xa);
            int idx = (d * 32 + r0) ^ (((d >> 1) & 3) << 3);
            *(unsigned*)&vt[idx] = w;
        }
    }
}

// ---------------------------------------------------------------------------
// fa_partial: flash partial over one K-split, double-buffered LDS staging.
// P never touches LDS: cvt_pk + permlane32_swap assemble the PV A-operand
// in registers (T12). LDS = 48KB -> 3 blocks/CU.
// ---------------------------------------------------------------------------
template <bool FINAL>
__global__ __launch_bounds__(256, 3) void fa_partial(
    const float* __restrict__ Qm, const short* __restrict__ kws,
    float* __restrict__ Opart, float* __restrict__ mlbuf, int tiles_per_split)
{
    __shared__ __align__(16) short buf[2][TILE_SHORTS];   // 2 x 24KB

    const int tid  = threadIdx.x;
    const int wid  = tid >> 6;
    const int lane = tid & 63;
    const int q32  = lane & 31;
    const int g    = lane >> 5;
    const int qb   = blockIdx.x;
    const int sp   = blockIdx.y;
    const int tile0 = sp * tiles_per_split;

    // ---- Q fragments: pre-scaled by CSC, split hi/lo bf16 (held in regs)
    s16x8 qh[8], ql[8];
    {
        const float* qrow = Qm + ((size_t)(qb * BQ_WG + wid * 32 + q32)) * DH + g * 8;
        #pragma unroll
        for (int c = 0; c < 8; ++c) {
            const float* p = qrow + c * 16;
            f32x4 v0 = *(const f32x4*)(p);
            f32x4 v1 = *(const f32x4*)(p + 4);
            #pragma unroll
            for (int j = 0; j < 8; ++j) {
                float x = ((j < 4) ? v0[j] : v1[j - 4]) * CSC;
                short h = f2bf(x);
                qh[c][j] = h;
                ql[c][j] = f2bf(x - bf2f(h));
            }
        }
    }

    f32x16 oacc[4];
    #pragma unroll
    for (int b = 0; b < 4; ++b)
        #pragma unroll
        for (int i = 0; i < 16; ++i) oacc[b][i] = 0.0f;
    float mrun = -INFINITY;
    float lrun = 0.0f;

#define STAGE(bb, tt) do {                                              \
        const short* gs_ = kws + (size_t)(tt) * TILE_SHORTS + tid * 8;  \
        short* ld_ = &buf[bb][tid * 8];                                 \
        _Pragma("unroll")                                               \
        for (int ch_ = 0; ch_ < 6; ++ch_)                               \
            gload16(gs_ + ch_ * 2048, ld_ + ch_ * 2048);                \
    } while (0)

    int cur = 0;
    STAGE(0, tile0);

    for (int t = 0; t < tiles_per_split; ++t) {
        __syncthreads();   // drains vmcnt (tile t ready) + all waves done with buf[cur^1]
        if (t + 1 < tiles_per_split) STAGE(cur ^ 1, tile0 + t + 1);

        const short* kh = &buf[cur][0];
        const short* kl = &buf[cur][4096];
        const short* vt = &buf[cur][8192];

        // ---- QK^T (swapped: S^T = K * Q^T), split-precision 3-MFMA
        f32x16 s;
        #pragma unroll
        for (int i = 0; i < 16; ++i) s[i] = 0.0f;
        #pragma unroll
        for (int c = 0; c < 8; ++c) {
            const int ia = (q32 * 128 + c * 16 + g * 8) ^ ((q32 & 7) << 3);
            s16x8 ah = *(const s16x8*)&kh[ia];
            s16x8 al = *(const s16x8*)&kl[ia];
            s = MFMA(ah, ql[c], s);   // hi*lo
            s = MFMA(al, qh[c], s);   // lo*hi
            s = MFMA(ah, qh[c], s);   // hi*hi
        }

        // ---- online softmax (lane owns q=q32; partner lane^32 has other 16 k's)
        float tmax = s[0];
        #pragma unroll
        for (int i = 1; i < 16; ++i) tmax = fmaxf(tmax, s[i]);
        tmax = fmaxf(tmax, __shfl_xor(tmax, 32));

        // T13 defer-max: only rescale when some row's max grew by > THR
        const bool resc = !__all(tmax <= mrun + RESC_THR);
        float mnew = mrun, alpha = 1.0f;
        if (resc) {
            mnew  = fmaxf(mrun, tmax);
            alpha = EXP2F(mrun - mnew);
            #pragma unroll
            for (int rI = 0; rI < 16; ++rI) {
                int qr = (rI & 3) + 8 * (rI >> 2) + 4 * g;
                float ar = __shfl(alpha, qr);
                #pragma unroll
                for (int b = 0; b < 4; ++b) oacc[b][rI] *= ar;
            }
        }
        float psum = 0.0f;
        #pragma unroll
        for (int i = 0; i < 16; ++i) { s[i] = EXP2F(s[i] - mnew); psum += s[i]; }
        psum += __shfl_xor(psum, 32);
        lrun = lrun * alpha + psum;
        mrun = mnew;

        // ---- T12: P -> bf16 packed words (k-adjacent pairs), in-register
        unsigned w[8];
        #pragma unroll
        for (int m = 0; m < 8; ++m)
            asm("v_cvt_pk_bf16_f32 %0, %1, %2"
                : "=v"(w[m]) : "v"(s[2 * m]), "v"(s[2 * m + 1]));
        // permlane32_swap: a' = {a.lo(own), b.lo(partner)}, b' = {a.hi(partner), b.hi(own)}
        unsigned a0 = w[0], b0 = w[2];
        asm("v_permlane32_swap_b32 %0, %1" : "+v"(a0), "+v"(b0));
        unsigned c0 = w[1], d0 = w[3];
        asm("v_permlane32_swap_b32 %0, %1" : "+v"(c0), "+v"(d0));
        unsigned e0 = w[4], f0 = w[6];
        asm("v_permlane32_swap_b32 %0, %1" : "+v"(e0), "+v"(f0));
        unsigned g0 = w[5], h0 = w[7];
        asm("v_permlane32_swap_b32 %0, %1" : "+v"(g0), "+v"(h0));
        union { s16x8 v; unsigned u[4]; } pa0, pa1;
        pa0.u[0] = a0; pa0.u[1] = c0; pa0.u[2] = b0; pa0.u[3] = d0;  // k = 0..15
        pa1.u[0] = e0; pa1.u[1] = g0; pa1.u[2] = f0; pa1.u[3] = h0;  // k = 16..31

        // ---- PV: O += P * V
        #pragma unroll
        for (int b = 0; b < 4; ++b) {
            const int d   = b * 32 + q32;
            const int swv = ((d >> 1) & 3) << 3;
            const int iv0 = (d * 32 + g * 8) ^ swv;
            const int iv1 = (d * 32 + 16 + g * 8) ^ swv;
            oacc[b] = MFMA(pa0.v, *(const s16x8*)&vt[iv0], oacc[b]);
            oacc[b] = MFMA(pa1.v, *(const s16x8*)&vt[iv1], oacc[b]);
        }
        cur ^= 1;
    }
#undef STAGE

    // ---- write partials (or final normalized output when single-split)
    if (FINAL) {
        const float inv = 1.0f / lrun;
        float* op = Opart + ((size_t)(qb * BQ_WG + wid * 32)) * DH;
        #pragma unroll
        for (int b = 0; b < 4; ++b)
            #pragma unroll
            for (int rI = 0; rI < 16; ++rI) {
                int qr = (rI & 3) + 8 * (rI >> 2) + 4 * g;
                float ir = __shfl(inv, qr);
                op[qr * DH + b * 32 + q32] = oacc[b][rI] * ir;
            }
    } else {
        float* op = Opart + ((size_t)sp * NROWS + qb * BQ_WG + wid * 32) * DH;
        #pragma unroll
        for (int b = 0; b < 4; ++b)
            #pragma unroll
            for (int rI = 0; rI < 16; ++rI) {
                int qr = (rI & 3) + 8 * (rI >> 2) + 4 * g;
                op[qr * DH + b * 32 + q32] = oacc[b][rI];
            }
        if (lane < 32) {
            float2* mlp = (float2*)mlbuf;
            mlp[(size_t)sp * NROWS + qb * BQ_WG + wid * 32 + q32] = make_float2(mrun, lrun);
        }
    }
}

// ---------------------------------------------------------------------------
// merge: compile-time NS => registers, no scratch
// ---------------------------------------------------------------------------
template <int NS>
__global__ __launch_bounds__(256) void fa_merge(const float* __restrict__ Opart,
                                               const float* __restrict__ mlbuf,
                                               float* __restrict__ out)
{
    int idx = blockIdx.x * 256 + threadIdx.x;
    int q   = idx >> 7;
    const float2* mlp = (const float2*)mlbuf;
    float2 mls[NS];
    float M = -INFINITY;
    #pragma unroll
    for (int s2 = 0; s2 < NS; ++s2) {
        mls[s2] = mlp[(size_t)s2 * NROWS + q];
        M = fmaxf(M, mls[s2].x);
    }
    float L = 0.0f, acc = 0.0f;
    #pragma unroll
    for (int s2 = 0; s2 < NS; ++s2) {
        float w = EXP2F(mls[s2].x - M);
        L   += w * mls[s2].y;
        acc += w * Opart[(size_t)s2 * NROWS * DH + idx];
    }
    out[idx] = acc / L;
}

extern "C" void kernel_launch(void* const* d_in, const int* in_sizes, int n_in,
                              void* d_out, int out_size, void* d_ws, size_t ws_size,
                              hipStream_t stream)
{
    const float* p1 = (const float*)d_in[0];
    const float* p2 = (const float*)d_in[1];
    float* out = (float*)d_out;

    const size_t kws_bytes  = (size_t)NTILES * TILE_SHORTS * sizeof(short);  // 6 MB
    const size_t per_split  = (size_t)NROWS * DH * sizeof(float)             // O partial
                            + (size_t)NROWS * 2 * sizeof(float);             // m,l

    int nsplit = 1;
    const int cand[3] = {8, 4, 2};
    for (int i = 0; i < 3; ++i)
        if (kws_bytes + (size_t)cand[i] * per_split <= ws_size) { nsplit = cand[i]; break; }

    short* kws = (short*)d_ws;
    prep<<<NTILES, 256, 0, stream>>>(p2, kws);

    if (nsplit == 1) {
        // minimal-ws fallback: single split, normalized output written directly
        dim3 grid1(NROWS / BQ_WG, 1);
        fa_partial<true><<<grid1, 256, 0, stream>>>(p1, kws, out, nullptr, NTILES);
        return;
    }

    float* Opart = (float*)((char*)d_ws + kws_bytes);
    float* mlbuf = Opart + (size_t)nsplit * NROWS * DH;

    dim3 grid1(NROWS / BQ_WG, nsplit);
    fa_partial<false><<<grid1, 256, 0, stream>>>(p1, kws, Opart, mlbuf, NTILES / nsplit);

    const int mgrid = (NROWS * DH) / 256;
    if (nsplit == 8)      fa_merge<8><<<mgrid, 256, 0, stream>>>(Opart, mlbuf, out);
    else if (nsplit == 4) fa_merge<4><<<mgrid, 256, 0, stream>>>(Opart, mlbuf, out);
    else                  fa_merge<2><<<mgrid, 256, 0, stream>>>(Opart, mlbuf, out);
}

// Round 6
// 156.954 us; speedup vs baseline: 1.1019x; 1.1019x over previous
//
#include <hip/hip_runtime.h>

#define NROWS 8192
#define DH 128
#define NTILES 256            // NROWS / 32
#define NWAVES 4
#define BQ_WG 128             // 4 waves * 32 q rows
#define TILE_SHORTS 12288     // 24KB per K tile: kh 4096 + kl 4096 + vt 4096 shorts

typedef float f32x16 __attribute__((ext_vector_type(16)));
typedef float f32x4  __attribute__((ext_vector_type(4)));
typedef short s16x8  __attribute__((ext_vector_type(8)));
typedef unsigned u32x4 __attribute__((ext_vector_type(4)));

#define MFMA(a, b, c) __builtin_amdgcn_mfma_f32_32x32x16_bf16(a, b, c, 0, 0, 0)
#define EXP2F(x) __builtin_amdgcn_exp2f(x)

// fp32 -> bf16 bits (RNE)
__device__ __forceinline__ short f2bf(float x) {
    unsigned u = __float_as_uint(x);
    unsigned r = (u + 0x7fffu + ((u >> 16) & 1u)) >> 16;
    return (short)r;
}
__device__ __forceinline__ float bf2f(short s) {
    return __uint_as_float(((unsigned)(unsigned short)s) << 16);
}

// log2-domain combined scale: sqrt(8192) * log2(e)
#define CSC 130.577849f
// defer-max threshold (log2 domain): P bounded by 2^8
#define RESC_THR 8.0f

__device__ __forceinline__ void gload16(const short* g, short* l) {
    __builtin_amdgcn_global_load_lds(
        (const __attribute__((address_space(1))) unsigned*)g,
        (__attribute__((address_space(3))) unsigned*)l, 16, 0, 0);
}

// ---------------------------------------------------------------------------
// prep: convert p2 (fp32) into per-tile swizzled LDS images in ws:
//   per 32-row tile t: [kh 8KB][kl 8KB][vt 8KB] contiguous (24KB)
//   kh/kl: idx = (r*128 + d) ^ ((r&15)<<3)          (short units; 4-bit swizzle)
//   vt   : idx = (d*32 + k) ^ (((d>>1)&3)<<3)       (short units, word writes)
// ---------------------------------------------------------------------------
__global__ __launch_bounds__(256) void prep(const float* __restrict__ KV,
                                            short* __restrict__ kws)
{
    const int t = blockIdx.x;
    const int tid = threadIdx.x;
    short* kh = kws + (size_t)t * TILE_SHORTS;
    short* kl = kh + 4096;
    short* vt = kh + 8192;

    // ---- Kh / Kl (each thread: one row-slice of 16 floats)
    {
        const int r  = tid >> 3;            // 0..31
        const int d0 = (tid & 7) << 4;      // 0,16,..,112
        const float* src = KV + ((size_t)(t * 32 + r)) * DH + d0;
        f32x4 a0 = *(const f32x4*)(src);
        f32x4 a1 = *(const f32x4*)(src + 4);
        f32x4 a2 = *(const f32x4*)(src + 8);
        f32x4 a3 = *(const f32x4*)(src + 12);
        s16x8 h0, h1, l0, l1;
        #pragma unroll
        for (int j = 0; j < 4; ++j) {
            { float x = a0[j]; short h = f2bf(x); h0[j]     = h; l0[j]     = f2bf(x - bf2f(h)); }
            { float x = a1[j]; short h = f2bf(x); h0[j + 4] = h; l0[j + 4] = f2bf(x - bf2f(h)); }
            { float x = a2[j]; short h = f2bf(x); h1[j]     = h; l1[j]     = f2bf(x - bf2f(h)); }
            { float x = a3[j]; short h = f2bf(x); h1[j + 4] = h; l1[j + 4] = f2bf(x - bf2f(h)); }
        }
        const int base = r * 128 + d0;
        const int swz  = (r & 15) << 3;
        *(s16x8*)&kh[(base    ) ^ swz] = h0;
        *(s16x8*)&kh[(base + 8) ^ swz] = h1;
        *(s16x8*)&kl[(base    ) ^ swz] = l0;
        *(s16x8*)&kl[(base + 8) ^ swz] = l1;
    }

    // ---- Vt (transposed bf16-hi of the same tile)
    {
        const int pr = tid & 15;        // row pair
        const int c8 = tid >> 4;        // d block
        const int r0 = pr * 2;
        const float* sa = KV + ((size_t)(t * 32 + r0)) * DH + c8 * 8;
        const float* sb = sa + DH;
        f32x4 a0 = *(const f32x4*)(sa);
        f32x4 a1 = *(const f32x4*)(sa + 4);
        f32x4 b0 = *(const f32x4*)(sb);
        f32x4 b1 = *(const f32x4*)(sb + 4);
        #pragma unroll
        for (int i = 0; i < 8; ++i) {
            int d = c8 * 8 + i;
            float xa = (i < 4) ? a0[i] : a1[i - 4];
            float xb = (i < 4) ? b0[i] : b1[i - 4];
            unsigned w = ((unsigned)(unsigned short)f2bf(xb) << 16) |
                         (unsigned short)f2bf(xa);
            int idx = (d * 32 + r0) ^ (((d >> 1) & 3) << 3);
            *(unsigned*)&vt[idx] = w;
        }
    }
}

// ---------------------------------------------------------------------------
// fa_partial: flash partial over one K-split, double-buffered LDS staging.
// P never touches LDS: cvt_pk + permlane32_swap assemble the PV A-operand
// in registers (T12). LDS = 48KB.
// ---------------------------------------------------------------------------
template <bool FINAL>
__global__ __launch_bounds__(256, 2) void fa_partial(
    const float* __restrict__ Qm, const short* __restrict__ kws,
    float* __restrict__ Opart, float* __restrict__ mlbuf, int tiles_per_split)
{
    __shared__ __align__(16) short buf[2][TILE_SHORTS];   // 2 x 24KB

    const int tid  = threadIdx.x;
    const int wid  = tid >> 6;
    const int lane = tid & 63;
    const int q32  = lane & 31;
    const int g    = lane >> 5;
    const int qb   = blockIdx.x;
    const int sp   = blockIdx.y;
    const int tile0 = sp * tiles_per_split;

    // ---- Q fragments: pre-scaled by CSC, split hi/lo bf16 (held in regs)
    s16x8 qh[8], ql[8];
    {
        const float* qrow = Qm + ((size_t)(qb * BQ_WG + wid * 32 + q32)) * DH + g * 8;
        #pragma unroll
        for (int c = 0; c < 8; ++c) {
            const float* p = qrow + c * 16;
            f32x4 v0 = *(const f32x4*)(p);
            f32x4 v1 = *(const f32x4*)(p + 4);
            #pragma unroll
            for (int j = 0; j < 8; ++j) {
                float x = ((j < 4) ? v0[j] : v1[j - 4]) * CSC;
                short h = f2bf(x);
                qh[c][j] = h;
                ql[c][j] = f2bf(x - bf2f(h));
            }
        }
    }

    f32x16 oacc[4];
    #pragma unroll
    for (int b = 0; b < 4; ++b)
        #pragma unroll
        for (int i = 0; i < 16; ++i) oacc[b][i] = 0.0f;
    float mrun = -INFINITY;
    float lrun = 0.0f;

#define STAGE(bb, tt) do {                                              \
        const short* gs_ = kws + (size_t)(tt) * TILE_SHORTS + tid * 8;  \
        short* ld_ = &buf[bb][tid * 8];                                 \
        _Pragma("unroll")                                               \
        for (int ch_ = 0; ch_ < 6; ++ch_)                               \
            gload16(gs_ + ch_ * 2048, ld_ + ch_ * 2048);                \
    } while (0)

    int cur = 0;
    STAGE(0, tile0);

    for (int t = 0; t < tiles_per_split; ++t) {
        __syncthreads();   // drains vmcnt (tile t ready) + all waves done with buf[cur^1]
        if (t + 1 < tiles_per_split) STAGE(cur ^ 1, tile0 + t + 1);

        const short* kh = &buf[cur][0];
        const short* kl = &buf[cur][4096];
        const short* vt = &buf[cur][8192];

        // ---- QK^T (swapped: S^T = K * Q^T), split-precision 3-MFMA
        f32x16 s;
        #pragma unroll
        for (int i = 0; i < 16; ++i) s[i] = 0.0f;
        #pragma unroll
        for (int c = 0; c < 8; ++c) {
            const int ia = (q32 * 128 + c * 16 + g * 8) ^ ((q32 & 15) << 3);
            s16x8 ah = *(const s16x8*)&kh[ia];
            s16x8 al = *(const s16x8*)&kl[ia];
            s = MFMA(ah, ql[c], s);   // hi*lo
            s = MFMA(al, qh[c], s);   // lo*hi
            s = MFMA(ah, qh[c], s);   // hi*hi
        }

        // ---- online softmax (lane owns q=q32; partner lane^32 has other 16 k's)
        float tmax = s[0];
        #pragma unroll
        for (int i = 1; i < 16; ++i) tmax = fmaxf(tmax, s[i]);
        tmax = fmaxf(tmax, __shfl_xor(tmax, 32));

        // T13 defer-max: only rescale when some row's max grew by > THR
        const bool resc = !__all(tmax <= mrun + RESC_THR);
        float mnew = mrun, alpha = 1.0f;
        if (resc) {
            mnew  = fmaxf(mrun, tmax);
            alpha = EXP2F(mrun - mnew);
            #pragma unroll
            for (int rI = 0; rI < 16; ++rI) {
                int qr = (rI & 3) + 8 * (rI >> 2) + 4 * g;
                float ar = __shfl(alpha, qr);
                #pragma unroll
                for (int b = 0; b < 4; ++b) oacc[b][rI] *= ar;
            }
        }
        float psum = 0.0f;
        #pragma unroll
        for (int i = 0; i < 16; ++i) { s[i] = EXP2F(s[i] - mnew); psum += s[i]; }
        psum += __shfl_xor(psum, 32);
        lrun = lrun * alpha + psum;
        mrun = mnew;

        // ---- T12: P -> bf16 packed words (k-adjacent pairs), in-register
        unsigned w[8];
        #pragma unroll
        for (int m = 0; m < 8; ++m)
            asm("v_cvt_pk_bf16_f32 %0, %1, %2"
                : "=v"(w[m]) : "v"(s[2 * m]), "v"(s[2 * m + 1]));
        // permlane32_swap: a' = {a.lo(own), b.lo(partner)}, b' = {a.hi(partner), b.hi(own)}
        unsigned a0 = w[0], b0 = w[2];
        asm("v_permlane32_swap_b32 %0, %1" : "+v"(a0), "+v"(b0));
        unsigned c0 = w[1], d0 = w[3];
        asm("v_permlane32_swap_b32 %0, %1" : "+v"(c0), "+v"(d0));
        unsigned e0 = w[4], f0 = w[6];
        asm("v_permlane32_swap_b32 %0, %1" : "+v"(e0), "+v"(f0));
        unsigned g0 = w[5], h0 = w[7];
        asm("v_permlane32_swap_b32 %0, %1" : "+v"(g0), "+v"(h0));
        // register-resident vector construction (no union -> no scratch)
        u32x4 pv0 = { a0, c0, b0, d0 };   // k = 0..15
        u32x4 pv1 = { e0, g0, f0, h0 };   // k = 16..31
        s16x8 pa0 = __builtin_bit_cast(s16x8, pv0);
        s16x8 pa1 = __builtin_bit_cast(s16x8, pv1);

        // ---- PV: O += P * V
        #pragma unroll
        for (int b = 0; b < 4; ++b) {
            const int d   = b * 32 + q32;
            const int swv = ((d >> 1) & 3) << 3;
            const int iv0 = (d * 32 + g * 8) ^ swv;
            const int iv1 = (d * 32 + 16 + g * 8) ^ swv;
            oacc[b] = MFMA(pa0, *(const s16x8*)&vt[iv0], oacc[b]);
            oacc[b] = MFMA(pa1, *(const s16x8*)&vt[iv1], oacc[b]);
        }
        cur ^= 1;
    }
#undef STAGE

    // ---- write partials (or final normalized output when single-split)
    if (FINAL) {
        const float inv = 1.0f / lrun;
        float* op = Opart + ((size_t)(qb * BQ_WG + wid * 32)) * DH;
        #pragma unroll
        for (int b = 0; b < 4; ++b)
            #pragma unroll
            for (int rI = 0; rI < 16; ++rI) {
                int qr = (rI & 3) + 8 * (rI >> 2) + 4 * g;
                float ir = __shfl(inv, qr);
                op[qr * DH + b * 32 + q32] = oacc[b][rI] * ir;
            }
    } else {
        float* op = Opart + ((size_t)sp * NROWS + qb * BQ_WG + wid * 32) * DH;
        #pragma unroll
        for (int b = 0; b < 4; ++b)
            #pragma unroll
            for (int rI = 0; rI < 16; ++rI) {
                int qr = (rI & 3) + 8 * (rI >> 2) + 4 * g;
                op[qr * DH + b * 32 + q32] = oacc[b][rI];
            }
        if (lane < 32) {
            float2* mlp = (float2*)mlbuf;
            mlp[(size_t)sp * NROWS + qb * BQ_WG + wid * 32 + q32] = make_float2(mrun, lrun);
        }
    }
}

// ---------------------------------------------------------------------------
// merge: compile-time NS => registers, no scratch
// ---------------------------------------------------------------------------
template <int NS>
__global__ __launch_bounds__(256) void fa_merge(const float* __restrict__ Opart,
                                               const float* __restrict__ mlbuf,
                                               float* __restrict__ out)
{
    int idx = blockIdx.x * 256 + threadIdx.x;
    int q   = idx >> 7;
    const float2* mlp = (const float2*)mlbuf;
    float2 mls[NS];
    float M = -INFINITY;
    #pragma unroll
    for (int s2 = 0; s2 < NS; ++s2) {
        mls[s2] = mlp[(size_t)s2 * NROWS + q];
        M = fmaxf(M, mls[s2].x);
    }
    float L = 0.0f, acc = 0.0f;
    #pragma unroll
    for (int s2 = 0; s2 < NS; ++s2) {
        float w = EXP2F(mls[s2].x - M);
        L   += w * mls[s2].y;
        acc += w * Opart[(size_t)s2 * NROWS * DH + idx];
    }
    out[idx] = acc / L;
}

extern "C" void kernel_launch(void* const* d_in, const int* in_sizes, int n_in,
                              void* d_out, int out_size, void* d_ws, size_t ws_size,
                              hipStream_t stream)
{
    const float* p1 = (const float*)d_in[0];
    const float* p2 = (const float*)d_in[1];
    float* out = (float*)d_out;

    const size_t kws_bytes  = (size_t)NTILES * TILE_SHORTS * sizeof(short);  // 6 MB
    const size_t per_split  = (size_t)NROWS * DH * sizeof(float)             // O partial
                            + (size_t)NROWS * 2 * sizeof(float);             // m,l

    int nsplit = 1;
    const int cand[4] = {16, 8, 4, 2};
    for (int i = 0; i < 4; ++i)
        if (kws_bytes + (size_t)cand[i] * per_split <= ws_size) { nsplit = cand[i]; break; }

    short* kws = (short*)d_ws;
    prep<<<NTILES, 256, 0, stream>>>(p2, kws);

    if (nsplit == 1) {
        // minimal-ws fallback: single split, normalized output written directly
        dim3 grid1(NROWS / BQ_WG, 1);
        fa_partial<true><<<grid1, 256, 0, stream>>>(p1, kws, out, nullptr, NTILES);
        return;
    }

    float* Opart = (float*)((char*)d_ws + kws_bytes);
    float* mlbuf = Opart + (size_t)nsplit * NROWS * DH;

    dim3 grid1(NROWS / BQ_WG, nsplit);
    fa_partial<false><<<grid1, 256, 0, stream>>>(p1, kws, Opart, mlbuf, NTILES / nsplit);

    const int mgrid = (NROWS * DH) / 256;
    if (nsplit == 16)     fa_merge<16><<<mgrid, 256, 0, stream>>>(Opart, mlbuf, out);
    else if (nsplit == 8) fa_merge<8><<<mgrid, 256, 0, stream>>>(Opart, mlbuf, out);
    else if (nsplit == 4) fa_merge<4><<<mgrid, 256, 0, stream>>>(Opart, mlbuf, out);
    else                  fa_merge<2><<<mgrid, 256, 0, stream>>>(Opart, mlbuf, out);
}

// Round 7
// 152.551 us; speedup vs baseline: 1.1337x; 1.0289x over previous
//
#include <hip/hip_runtime.h>

#define NROWS 8192
#define DH 128
#define NTILES 256            // NROWS / 32
#define NWAVES 4
#define BQ_WG 128             // 4 waves * 32 q rows
#define TILE_SHORTS 12288     // 24KB per K tile: kh 4096 + kl 4096 + vt 4096 shorts

typedef float f32x16 __attribute__((ext_vector_type(16)));
typedef float f32x4  __attribute__((ext_vector_type(4)));
typedef short s16x8  __attribute__((ext_vector_type(8)));
typedef unsigned u32x4 __attribute__((ext_vector_type(4)));

#define MFMA(a, b, c) __builtin_amdgcn_mfma_f32_32x32x16_bf16(a, b, c, 0, 0, 0)
#define EXP2F(x) __builtin_amdgcn_exp2f(x)

// fp32 -> bf16 bits (RNE)
__device__ __forceinline__ short f2bf(float x) {
    unsigned u = __float_as_uint(x);
    unsigned r = (u + 0x7fffu + ((u >> 16) & 1u)) >> 16;
    return (short)r;
}
__device__ __forceinline__ float bf2f(short s) {
    return __uint_as_float(((unsigned)(unsigned short)s) << 16);
}
__device__ __forceinline__ float bf2f_u(unsigned short s) {
    return __uint_as_float(((unsigned)s) << 16);
}

// log2-domain combined scale: sqrt(8192) * log2(e)
#define CSC 130.577849f
// defer-max threshold (log2 domain): P bounded by 2^8
#define RESC_THR 8.0f

__device__ __forceinline__ void gload16(const short* g, short* l) {
    __builtin_amdgcn_global_load_lds(
        (const __attribute__((address_space(1))) unsigned*)g,
        (__attribute__((address_space(3))) unsigned*)l, 16, 0, 0);
}

// ---------------------------------------------------------------------------
// prep: convert p2 (fp32) into per-tile swizzled LDS images in ws:
//   per 32-row tile t: [kh 8KB][kl 8KB][vt 8KB] contiguous (24KB)
//   kh/kl: idx = (r*128 + d) ^ ((r&15)<<3)          (short units; 4-bit swizzle)
//   vt   : idx = (d*32 + k) ^ (((d>>1)&3)<<3)       (short units, word writes)
// ---------------------------------------------------------------------------
__global__ __launch_bounds__(256) void prep(const float* __restrict__ KV,
                                            short* __restrict__ kws)
{
    const int t = blockIdx.x;
    const int tid = threadIdx.x;
    short* kh = kws + (size_t)t * TILE_SHORTS;
    short* kl = kh + 4096;
    short* vt = kh + 8192;

    // ---- Kh / Kl (each thread: one row-slice of 16 floats)
    {
        const int r  = tid >> 3;            // 0..31
        const int d0 = (tid & 7) << 4;      // 0,16,..,112
        const float* src = KV + ((size_t)(t * 32 + r)) * DH + d0;
        f32x4 a0 = *(const f32x4*)(src);
        f32x4 a1 = *(const f32x4*)(src + 4);
        f32x4 a2 = *(const f32x4*)(src + 8);
        f32x4 a3 = *(const f32x4*)(src + 12);
        s16x8 h0, h1, l0, l1;
        #pragma unroll
        for (int j = 0; j < 4; ++j) {
            { float x = a0[j]; short h = f2bf(x); h0[j]     = h; l0[j]     = f2bf(x - bf2f(h)); }
            { float x = a1[j]; short h = f2bf(x); h0[j + 4] = h; l0[j + 4] = f2bf(x - bf2f(h)); }
            { float x = a2[j]; short h = f2bf(x); h1[j]     = h; l1[j]     = f2bf(x - bf2f(h)); }
            { float x = a3[j]; short h = f2bf(x); h1[j + 4] = h; l1[j + 4] = f2bf(x - bf2f(h)); }
        }
        const int base = r * 128 + d0;
        const int swz  = (r & 15) << 3;
        *(s16x8*)&kh[(base    ) ^ swz] = h0;
        *(s16x8*)&kh[(base + 8) ^ swz] = h1;
        *(s16x8*)&kl[(base    ) ^ swz] = l0;
        *(s16x8*)&kl[(base + 8) ^ swz] = l1;
    }

    // ---- Vt (transposed bf16-hi of the same tile)
    {
        const int pr = tid & 15;        // row pair
        const int c8 = tid >> 4;        // d block
        const int r0 = pr * 2;
        const float* sa = KV + ((size_t)(t * 32 + r0)) * DH + c8 * 8;
        const float* sb = sa + DH;
        f32x4 a0 = *(const f32x4*)(sa);
        f32x4 a1 = *(const f32x4*)(sa + 4);
        f32x4 b0 = *(const f32x4*)(sb);
        f32x4 b1 = *(const f32x4*)(sb + 4);
        #pragma unroll
        for (int i = 0; i < 8; ++i) {
            int d = c8 * 8 + i;
            float xa = (i < 4) ? a0[i] : a1[i - 4];
            float xb = (i < 4) ? b0[i] : b1[i - 4];
            unsigned w = ((unsigned)(unsigned short)f2bf(xb) << 16) |
                         (unsigned short)f2bf(xa);
            int idx = (d * 32 + r0) ^ (((d >> 1) & 3) << 3);
            *(unsigned*)&vt[idx] = w;
        }
    }
}

// ---------------------------------------------------------------------------
// fa_partial: flash partial over one K-split, double-buffered LDS staging.
// QK^T uses 3 INDEPENDENT accumulator chains (depth 8 instead of 24) so
// dependent-MFMA latency can be hidden. P stays in registers (T12).
// ---------------------------------------------------------------------------
template <bool FINAL>
__global__ __launch_bounds__(256, 2) void fa_partial(
    const float* __restrict__ Qm, const short* __restrict__ kws,
    unsigned short* __restrict__ Opart, float* __restrict__ outF,
    float* __restrict__ mlbuf, int tiles_per_split)
{
    __shared__ __align__(16) short buf[2][TILE_SHORTS];   // 2 x 24KB

    const int tid  = threadIdx.x;
    const int wid  = tid >> 6;
    const int lane = tid & 63;
    const int q32  = lane & 31;
    const int g    = lane >> 5;
    const int qb   = blockIdx.x;
    const int sp   = blockIdx.y;
    const int tile0 = sp * tiles_per_split;

    // ---- Q fragments: pre-scaled by CSC, split hi/lo bf16 (held in regs)
    s16x8 qh[8], ql[8];
    {
        const float* qrow = Qm + ((size_t)(qb * BQ_WG + wid * 32 + q32)) * DH + g * 8;
        #pragma unroll
        for (int c = 0; c < 8; ++c) {
            const float* p = qrow + c * 16;
            f32x4 v0 = *(const f32x4*)(p);
            f32x4 v1 = *(const f32x4*)(p + 4);
            #pragma unroll
            for (int j = 0; j < 8; ++j) {
                float x = ((j < 4) ? v0[j] : v1[j - 4]) * CSC;
                short h = f2bf(x);
                qh[c][j] = h;
                ql[c][j] = f2bf(x - bf2f(h));
            }
        }
    }

    f32x16 oacc[4];
    #pragma unroll
    for (int b = 0; b < 4; ++b)
        #pragma unroll
        for (int i = 0; i < 16; ++i) oacc[b][i] = 0.0f;
    float mrun = -INFINITY;
    float lrun = 0.0f;

#define STAGE(bb, tt) do {                                              \
        const short* gs_ = kws + (size_t)(tt) * TILE_SHORTS + tid * 8;  \
        short* ld_ = &buf[bb][tid * 8];                                 \
        _Pragma("unroll")                                               \
        for (int ch_ = 0; ch_ < 6; ++ch_)                               \
            gload16(gs_ + ch_ * 2048, ld_ + ch_ * 2048);                \
    } while (0)

    int cur = 0;
    STAGE(0, tile0);

    for (int t = 0; t < tiles_per_split; ++t) {
        __syncthreads();   // drains vmcnt (tile t ready) + all waves done with buf[cur^1]
        if (t + 1 < tiles_per_split) STAGE(cur ^ 1, tile0 + t + 1);

        const short* kh = &buf[cur][0];
        const short* kl = &buf[cur][4096];
        const short* vt = &buf[cur][8192];

        // ---- QK^T (swapped: S^T = K * Q^T), split-precision 3-MFMA.
        // Three independent chains (depth 8) -> latency hideable.
        f32x16 sA, sB, sC;
        #pragma unroll
        for (int i = 0; i < 16; ++i) { sA[i] = 0.0f; sB[i] = 0.0f; sC[i] = 0.0f; }
        #pragma unroll
        for (int c = 0; c < 8; ++c) {
            const int ia = (q32 * 128 + c * 16 + g * 8) ^ ((q32 & 15) << 3);
            s16x8 ah = *(const s16x8*)&kh[ia];
            s16x8 al = *(const s16x8*)&kl[ia];
            sA = MFMA(ah, qh[c], sA);   // hi*hi
            sB = MFMA(ah, ql[c], sB);   // hi*lo
            sC = MFMA(al, qh[c], sC);   // lo*hi
        }
        f32x16 s = sA + sB + sC;

        // ---- online softmax (lane owns q=q32; partner lane^32 has other 16 k's)
        float tmax = s[0];
        #pragma unroll
        for (int i = 1; i < 16; ++i) tmax = fmaxf(tmax, s[i]);
        tmax = fmaxf(tmax, __shfl_xor(tmax, 32));

        // T13 defer-max: only rescale when some row's max grew by > THR
        const bool resc = !__all(tmax <= mrun + RESC_THR);
        float mnew = mrun, alpha = 1.0f;
        if (resc) {
            mnew  = fmaxf(mrun, tmax);
            alpha = EXP2F(mrun - mnew);
            #pragma unroll
            for (int rI = 0; rI < 16; ++rI) {
                int qr = (rI & 3) + 8 * (rI >> 2) + 4 * g;
                float ar = __shfl(alpha, qr);
                #pragma unroll
                for (int b = 0; b < 4; ++b) oacc[b][rI] *= ar;
            }
        }
        float psum = 0.0f;
        #pragma unroll
        for (int i = 0; i < 16; ++i) { s[i] = EXP2F(s[i] - mnew); psum += s[i]; }
        psum += __shfl_xor(psum, 32);
        lrun = lrun * alpha + psum;
        mrun = mnew;

        // ---- T12: P -> bf16 packed words (k-adjacent pairs), in-register
        unsigned w[8];
        #pragma unroll
        for (int m = 0; m < 8; ++m)
            asm("v_cvt_pk_bf16_f32 %0, %1, %2"
                : "=v"(w[m]) : "v"(s[2 * m]), "v"(s[2 * m + 1]));
        // permlane32_swap: a' = {a.lo(own), b.lo(partner)}, b' = {a.hi(partner), b.hi(own)}
        unsigned a0 = w[0], b0 = w[2];
        asm("v_permlane32_swap_b32 %0, %1" : "+v"(a0), "+v"(b0));
        unsigned c0 = w[1], d0 = w[3];
        asm("v_permlane32_swap_b32 %0, %1" : "+v"(c0), "+v"(d0));
        unsigned e0 = w[4], f0 = w[6];
        asm("v_permlane32_swap_b32 %0, %1" : "+v"(e0), "+v"(f0));
        unsigned g0 = w[5], h0 = w[7];
        asm("v_permlane32_swap_b32 %0, %1" : "+v"(g0), "+v"(h0));
        // register-resident vector construction (no union -> no scratch)
        u32x4 pv0 = { a0, c0, b0, d0 };   // k = 0..15
        u32x4 pv1 = { e0, g0, f0, h0 };   // k = 16..31
        s16x8 pa0 = __builtin_bit_cast(s16x8, pv0);
        s16x8 pa1 = __builtin_bit_cast(s16x8, pv1);

        // ---- PV: O += P * V
        #pragma unroll
        for (int b = 0; b < 4; ++b) {
            const int d   = b * 32 + q32;
            const int swv = ((d >> 1) & 3) << 3;
            const int iv0 = (d * 32 + g * 8) ^ swv;
            const int iv1 = (d * 32 + 16 + g * 8) ^ swv;
            oacc[b] = MFMA(pa0, *(const s16x8*)&vt[iv0], oacc[b]);
            oacc[b] = MFMA(pa1, *(const s16x8*)&vt[iv1], oacc[b]);
        }
        cur ^= 1;
    }
#undef STAGE

    // ---- write partials (bf16) or final normalized output (fp32)
    if (FINAL) {
        const float inv = 1.0f / lrun;
        float* op = outF + ((size_t)(qb * BQ_WG + wid * 32)) * DH;
        #pragma unroll
        for (int b = 0; b < 4; ++b)
            #pragma unroll
            for (int rI = 0; rI < 16; ++rI) {
                int qr = (rI & 3) + 8 * (rI >> 2) + 4 * g;
                float ir = __shfl(inv, qr);
                op[qr * DH + b * 32 + q32] = oacc[b][rI] * ir;
            }
    } else {
        unsigned short* op = Opart + ((size_t)sp * NROWS + qb * BQ_WG + wid * 32) * DH;
        #pragma unroll
        for (int b = 0; b < 4; ++b)
            #pragma unroll
            for (int rI = 0; rI < 16; ++rI) {
                int qr = (rI & 3) + 8 * (rI >> 2) + 4 * g;
                op[qr * DH + b * 32 + q32] = (unsigned short)f2bf(oacc[b][rI]);
            }
        if (lane < 32) {
            float2* mlp = (float2*)mlbuf;
            mlp[(size_t)sp * NROWS + qb * BQ_WG + wid * 32 + q32] = make_float2(mrun, lrun);
        }
    }
}

// ---------------------------------------------------------------------------
// merge: compile-time NS => registers, no scratch; bf16 partials
// ---------------------------------------------------------------------------
template <int NS>
__global__ __launch_bounds__(256) void fa_merge(const unsigned short* __restrict__ Opart,
                                               const float* __restrict__ mlbuf,
                                               float* __restrict__ out)
{
    int idx = blockIdx.x * 256 + threadIdx.x;
    int q   = idx >> 7;
    const float2* mlp = (const float2*)mlbuf;
    float2 mls[NS];
    float M = -INFINITY;
    #pragma unroll
    for (int s2 = 0; s2 < NS; ++s2) {
        mls[s2] = mlp[(size_t)s2 * NROWS + q];
        M = fmaxf(M, mls[s2].x);
    }
    float L = 0.0f, acc = 0.0f;
    #pragma unroll
    for (int s2 = 0; s2 < NS; ++s2) {
        float w = EXP2F(mls[s2].x - M);
        L   += w * mls[s2].y;
        acc += w * bf2f_u(Opart[(size_t)s2 * NROWS * DH + idx]);
    }
    out[idx] = acc / L;
}

extern "C" void kernel_launch(void* const* d_in, const int* in_sizes, int n_in,
                              void* d_out, int out_size, void* d_ws, size_t ws_size,
                              hipStream_t stream)
{
    const float* p1 = (const float*)d_in[0];
    const float* p2 = (const float*)d_in[1];
    float* out = (float*)d_out;

    const size_t kws_bytes  = (size_t)NTILES * TILE_SHORTS * sizeof(short);  // 6 MB
    const size_t per_split  = (size_t)NROWS * DH * sizeof(unsigned short)    // O partial bf16
                            + (size_t)NROWS * 2 * sizeof(float);             // m,l

    int nsplit = 1;
    const int cand[4] = {16, 8, 4, 2};
    for (int i = 0; i < 4; ++i)
        if (kws_bytes + (size_t)cand[i] * per_split <= ws_size) { nsplit = cand[i]; break; }

    short* kws = (short*)d_ws;
    prep<<<NTILES, 256, 0, stream>>>(p2, kws);

    if (nsplit == 1) {
        // minimal-ws fallback: single split, normalized output written directly
        dim3 grid1(NROWS / BQ_WG, 1);
        fa_partial<true><<<grid1, 256, 0, stream>>>(p1, kws, nullptr, out, nullptr, NTILES);
        return;
    }

    unsigned short* Opart = (unsigned short*)((char*)d_ws + kws_bytes);
    float* mlbuf = (float*)(Opart + (size_t)nsplit * NROWS * DH);

    dim3 grid1(NROWS / BQ_WG, nsplit);
    fa_partial<false><<<grid1, 256, 0, stream>>>(p1, kws, Opart, nullptr, mlbuf, NTILES / nsplit);

    const int mgrid = (NROWS * DH) / 256;
    if (nsplit == 16)     fa_merge<16><<<mgrid, 256, 0, stream>>>(Opart, mlbuf, out);
    else if (nsplit == 8) fa_merge<8><<<mgrid, 256, 0, stream>>>(Opart, mlbuf, out);
    else if (nsplit == 4) fa_merge<4><<<mgrid, 256, 0, stream>>>(Opart, mlbuf, out);
    else                  fa_merge<2><<<mgrid, 256, 0, stream>>>(Opart, mlbuf, out);
}